// Round 8
// baseline (125.376 us; speedup 1.0000x reference)
//
#include <hip/hip_runtime.h>
#include <math.h>

typedef float f32x4 __attribute__((ext_vector_type(4)));

#define NB 768              // one block per (b,c) plane
#define BS 256
#define NBATCH 64
#define NCH 12
#define NQ 4
#define PLANE 65536         // floats per plane
#define PLANE4 16384        // f32x4 per plane
#define IT 64               // f32x4 per thread per plane
#define CNT_STRIDE 32       // ints -> one 128-B cacheline per counter

#define LOAD_A(p)    __hip_atomic_load((p),  __ATOMIC_RELAXED, __HIP_MEMORY_SCOPE_AGENT)
#define STORE_A(p,v) __hip_atomic_store((p), (v), __ATOMIC_RELAXED, __HIP_MEMORY_SCOPE_AGENT)

// ---------------- VQC gate helpers (all indices compile-time) ----------------
__device__ __forceinline__ void apply_rz(float* sr, float* si, int mask, float theta) {
    float c, s;
    __sincosf(0.5f * theta, &s, &c);
    #pragma unroll
    for (int i = 0; i < 16; ++i) {
        float r = sr[i], im = si[i];
        if (i & mask) { sr[i] = r * c - im * s; si[i] = im * c + r * s; }
        else          { sr[i] = r * c + im * s; si[i] = im * c - r * s; }
    }
}

__device__ __forceinline__ void apply_ry(float* sr, float* si, int mask, float theta) {
    float c, s;
    __sincosf(0.5f * theta, &s, &c);
    #pragma unroll
    for (int i = 0; i < 16; ++i) {
        if (i & mask) continue;
        int jj = i | mask;
        float r0 = sr[i], i0 = si[i], r1 = sr[jj], i1 = si[jj];
        sr[i]  = c * r0 - s * r1;  si[i]  = c * i0 - s * i1;
        sr[jj] = s * r0 + c * r1;  si[jj] = s * i0 + c * i1;
    }
}

__device__ __forceinline__ void apply_cnot(float* sr, float* si, int mc, int mt) {
    #pragma unroll
    for (int i = 0; i < 16; ++i) {
        if ((i & mc) && !(i & mt)) {
            int jj = i | mt;
            float tr = sr[i], ti = si[i];
            sr[i] = sr[jj]; si[i] = si[jj];
            sr[jj] = tr;    si[jj] = ti;
        }
    }
}

__device__ __forceinline__ void apply_u3(float* sr, float* si, int mask,
                                         float theta, float phi, float lam) {
    float c = __cosf(0.5f * theta), s = __sinf(0.5f * theta);
    float cl, sl, cp, sp, cpl, spl;
    __sincosf(lam, &sl, &cl);
    __sincosf(phi, &sp, &cp);
    __sincosf(phi + lam, &spl, &cpl);
    float u01r = -cl * s, u01i = -sl * s;
    float u10r =  cp * s, u10i =  sp * s;
    float u11r =  cpl * c, u11i = spl * c;
    #pragma unroll
    for (int i = 0; i < 16; ++i) {
        if (i & mask) continue;
        int jj = i | mask;
        float r0 = sr[i], i0 = si[i], r1 = sr[jj], i1 = si[jj];
        sr[i]  = c * r0 + (u01r * r1 - u01i * i1);
        si[i]  = c * i0 + (u01r * i1 + u01i * r1);
        sr[jj] = (u10r * r0 - u10i * i0) + (u11r * r1 - u11i * i1);
        si[jj] = (u10r * i0 + u10i * r0) + (u11r * i1 + u11i * r1);
    }
}

// ---------------- Fused: per-plane mean -> padded 12-block sync -> VQC -> scale ----
// ws: cnt[64*CNT_STRIDE] ints (padded, zeroed each launch) | meanbuf[768] floats
__global__ __launch_bounds__(BS, 4) void fused_kernel(
        const float* __restrict__ x, const float* __restrict__ w,
        const float* __restrict__ fcw, const float* __restrict__ fcb,
        float* __restrict__ out, int* __restrict__ cnt,
        float* __restrict__ meanbuf)
{
    const int p = blockIdx.x;            // plane index = b*12 + c
    const int b = p / NCH, c = p - b * NCH;
    const int t = threadIdx.x;
    const int lane = t & 63, wid = t >> 6;

    const f32x4* xp = reinterpret_cast<const f32x4*>(x) + (size_t)p * PLANE4;
    f32x4*       op = reinterpret_cast<f32x4*>(out)     + (size_t)p * PLANE4;

    // ---- phase 1: mean of my plane (temporal loads warm L2/L3 for phase 2) ----
    float s0 = 0.f, s1 = 0.f, s2 = 0.f, s3 = 0.f;
    for (int i = 0; i < IT; i += 4) {
        f32x4 a = xp[t + (i + 0) * BS];
        f32x4 d = xp[t + (i + 1) * BS];
        f32x4 e = xp[t + (i + 2) * BS];
        f32x4 f = xp[t + (i + 3) * BS];
        s0 += (a.x + a.y) + (a.z + a.w);
        s1 += (d.x + d.y) + (d.z + d.w);
        s2 += (e.x + e.y) + (e.z + e.w);
        s3 += (f.x + f.y) + (f.z + f.w);
    }
    float sum = (s0 + s1) + (s2 + s3);
    #pragma unroll
    for (int off = 32; off; off >>= 1) sum += __shfl_xor(sum, off);
    __shared__ float wsum[4];
    if (lane == 0) wsum[wid] = sum;
    __syncthreads();

    // ---- publish mean; sync the 12 blocks of batch b on a private cacheline ----
    int* cb = &cnt[b * CNT_STRIDE];
    if (t == 0) {
        float tot = (wsum[0] + wsum[1]) + (wsum[2] + wsum[3]);
        STORE_A(&meanbuf[p], tot * (1.0f / (float)PLANE));
        __hip_atomic_fetch_add(cb, 1, __ATOMIC_ACQ_REL, __HIP_MEMORY_SCOPE_AGENT);
        while (__hip_atomic_load(cb, __ATOMIC_ACQUIRE, __HIP_MEMORY_SCOPE_AGENT) < NCH)
            __builtin_amdgcn_s_sleep(8);   // ~512-cycle backoff between polls
    }
    __syncthreads();   // all threads ordered after t0's acquire

    // ---- VQC for batch b (block-uniform, redundant per thread) ----
    float m[NCH];
    #pragma unroll
    for (int cc = 0; cc < NCH; ++cc) m[cc] = LOAD_A(&meanbuf[b * NCH + cc]);

    float sr[16], si[16];
    #pragma unroll
    for (int i = 0; i < 16; ++i) { sr[i] = 0.25f; si[i] = 0.f; }
    #pragma unroll
    for (int q = 0; q < NQ; ++q) {
        const int mask = 1 << (3 - q);
        apply_rz(sr, si, mask, m[q * 3 + 0]);
        apply_ry(sr, si, mask, m[q * 3 + 1]);
        apply_rz(sr, si, mask, m[q * 3 + 2]);
    }
    apply_cnot(sr, si, 1 << 3, 1 << 2);
    apply_cnot(sr, si, 1 << 2, 1 << 1);
    apply_cnot(sr, si, 1 << 1, 1 << 0);
    apply_cnot(sr, si, 1 << 0, 1 << 3);
    #pragma unroll
    for (int q = 0; q < NQ; ++q) {
        const int mask = 1 << (3 - q);
        apply_u3(sr, si, mask, w[q * 3 + 0], w[q * 3 + 1], w[q * 3 + 2]);
    }
    float z[NQ];
    #pragma unroll
    for (int q = 0; q < NQ; ++q) {
        const int mask = 1 << (3 - q);
        float acc = 0.f;
        #pragma unroll
        for (int i = 0; i < 16; ++i) {
            float pr = sr[i] * sr[i] + si[i] * si[i];
            acc += (i & mask) ? -pr : pr;
        }
        z[q] = acc;
    }
    float a = fcb[c];
    #pragma unroll
    for (int q = 0; q < NQ; ++q) a += z[q] * fcw[c * NQ + q];
    const float att = 1.0f / (1.0f + expf(-a));

    // ---- phase 2: re-read my plane (L2/L3-hot) * att -> NT store ----
    #pragma unroll 4
    for (int i = 0; i < IT; ++i) {
        f32x4 v = xp[t + i * BS];
        __builtin_nontemporal_store(v * att, &op[t + i * BS]);
    }
}

extern "C" void kernel_launch(void* const* d_in, const int* in_sizes, int n_in,
                              void* d_out, int out_size, void* d_ws, size_t ws_size,
                              hipStream_t stream) {
    const float* x   = (const float*)d_in[0];
    const float* vw  = (const float*)d_in[1];
    const float* fcw = (const float*)d_in[2];
    const float* fcb = (const float*)d_in[3];
    float* out = (float*)d_out;

    int*   cnt     = (int*)d_ws;                      // [64 * CNT_STRIDE], padded
    float* meanbuf = (float*)((char*)d_ws + NBATCH * CNT_STRIDE * sizeof(int));

    hipMemsetAsync(cnt, 0, NBATCH * CNT_STRIDE * sizeof(int), stream);  // per-replay re-init
    fused_kernel<<<dim3(NB), dim3(BS), 0, stream>>>(x, vw, fcw, fcb, out, cnt, meanbuf);
}

// Round 9
// 94.821 us; speedup vs baseline: 1.3222x; 1.3222x over previous
//
#include <hip/hip_runtime.h>
#include <math.h>

typedef float f32x4 __attribute__((ext_vector_type(4)));

#define NSEG 3072           // kernel 1: 4 segments per plane
#define SEG4 4096           // f32x4 per segment
#define NB 768              // kernel 2: one block per (b,c) plane
#define BS 256
#define NCH 12
#define NQ 4
#define PLANE 65536         // floats per plane
#define PLANE4 16384        // f32x4 per plane
#define PF 8                // prefetched f32x4 per thread in kernel 2

// ---------------- VQC gate helpers (all indices compile-time) ----------------
__device__ __forceinline__ void apply_rz(float* sr, float* si, int mask, float theta) {
    float c, s;
    __sincosf(0.5f * theta, &s, &c);
    #pragma unroll
    for (int i = 0; i < 16; ++i) {
        float r = sr[i], im = si[i];
        if (i & mask) { sr[i] = r * c - im * s; si[i] = im * c + r * s; }
        else          { sr[i] = r * c + im * s; si[i] = im * c - r * s; }
    }
}

__device__ __forceinline__ void apply_ry(float* sr, float* si, int mask, float theta) {
    float c, s;
    __sincosf(0.5f * theta, &s, &c);
    #pragma unroll
    for (int i = 0; i < 16; ++i) {
        if (i & mask) continue;
        int jj = i | mask;
        float r0 = sr[i], i0 = si[i], r1 = sr[jj], i1 = si[jj];
        sr[i]  = c * r0 - s * r1;  si[i]  = c * i0 - s * i1;
        sr[jj] = s * r0 + c * r1;  si[jj] = s * i0 + c * i1;
    }
}

__device__ __forceinline__ void apply_cnot(float* sr, float* si, int mc, int mt) {
    #pragma unroll
    for (int i = 0; i < 16; ++i) {
        if ((i & mc) && !(i & mt)) {
            int jj = i | mt;
            float tr = sr[i], ti = si[i];
            sr[i] = sr[jj]; si[i] = si[jj];
            sr[jj] = tr;    si[jj] = ti;
        }
    }
}

__device__ __forceinline__ void apply_u3(float* sr, float* si, int mask,
                                         float theta, float phi, float lam) {
    float c = __cosf(0.5f * theta), s = __sinf(0.5f * theta);
    float cl, sl, cp, sp, cpl, spl;
    __sincosf(lam, &sl, &cl);
    __sincosf(phi, &sp, &cp);
    __sincosf(phi + lam, &spl, &cpl);
    float u01r = -cl * s, u01i = -sl * s;
    float u10r =  cp * s, u10i =  sp * s;
    float u11r =  cpl * c, u11i = spl * c;
    #pragma unroll
    for (int i = 0; i < 16; ++i) {
        if (i & mask) continue;
        int jj = i | mask;
        float r0 = sr[i], i0 = si[i], r1 = sr[jj], i1 = si[jj];
        sr[i]  = c * r0 + (u01r * r1 - u01i * i1);
        si[i]  = c * i0 + (u01r * i1 + u01i * r1);
        sr[jj] = (u10r * r0 - u10i * i0) + (u11r * r1 - u11i * i1);
        si[jj] = (u10r * i0 + u10i * r0) + (u11r * i1 + u11i * r1);
    }
}

// ---------------- Kernel 1: per-segment partial sums (temporal loads warm L3) ----
__global__ __launch_bounds__(256) void mean_partial(const float* __restrict__ x,
                                                    float* __restrict__ part) {
    const int seg = blockIdx.x;
    const f32x4* p = reinterpret_cast<const f32x4*>(x) + (size_t)seg * SEG4;
    const int t = threadIdx.x;
    float s0 = 0.f, s1 = 0.f, s2 = 0.f, s3 = 0.f;
    #pragma unroll
    for (int i = 0; i < 16; i += 4) {
        f32x4 a = p[t + (i + 0) * 256];
        f32x4 b = p[t + (i + 1) * 256];
        f32x4 c = p[t + (i + 2) * 256];
        f32x4 d = p[t + (i + 3) * 256];
        s0 += (a.x + a.y) + (a.z + a.w);
        s1 += (b.x + b.y) + (b.z + b.w);
        s2 += (c.x + c.y) + (c.z + c.w);
        s3 += (d.x + d.y) + (d.z + d.w);
    }
    float sum = (s0 + s1) + (s2 + s3);
    #pragma unroll
    for (int off = 32; off; off >>= 1) sum += __shfl_down(sum, off);
    __shared__ float wsum[4];
    if ((threadIdx.x & 63) == 0) wsum[threadIdx.x >> 6] = sum;
    __syncthreads();
    if (threadIdx.x == 0) part[seg] = (wsum[0] + wsum[1]) + (wsum[2] + wsum[3]);
}

// ---------------- Kernel 2: prefetch || wave0-VQC -> broadcast att -> stream ----
__global__ __launch_bounds__(256) void scale_vqc(const float* __restrict__ x,
                                                 const float* __restrict__ part,
                                                 const float* __restrict__ w,
                                                 const float* __restrict__ fcw,
                                                 const float* __restrict__ fcb,
                                                 float* __restrict__ out) {
    const int p = blockIdx.x;            // plane = b*12 + c
    const int b = p / NCH, c = p - b * NCH;
    const int t = threadIdx.x;
    __shared__ float s_att;

    const f32x4* xp = reinterpret_cast<const f32x4*>(x) + (size_t)p * PLANE4;
    f32x4*       op = reinterpret_cast<f32x4*>(out)     + (size_t)p * PLANE4;

    // issue prefetch loads first — in flight during wave0's VQC
    f32x4 h0 = xp[t + 0 * BS], h1 = xp[t + 1 * BS];
    f32x4 h2 = xp[t + 2 * BS], h3 = xp[t + 3 * BS];
    f32x4 h4 = xp[t + 4 * BS], h5 = xp[t + 5 * BS];
    f32x4 h6 = xp[t + 6 * BS], h7 = xp[t + 7 * BS];

    if (t < 64) {   // wave 0 only: VQC (redundant across its 64 lanes)
        float m[NCH];
        #pragma unroll
        for (int cc = 0; cc < NCH; ++cc) {
            const float* q = &part[(size_t)(b * NCH + cc) * 4];
            m[cc] = ((q[0] + q[1]) + (q[2] + q[3])) * (1.0f / (float)PLANE);
        }
        float sr[16], si[16];
        #pragma unroll
        for (int i = 0; i < 16; ++i) { sr[i] = 0.25f; si[i] = 0.f; }
        #pragma unroll
        for (int q = 0; q < NQ; ++q) {
            const int mask = 1 << (3 - q);
            apply_rz(sr, si, mask, m[q * 3 + 0]);
            apply_ry(sr, si, mask, m[q * 3 + 1]);
            apply_rz(sr, si, mask, m[q * 3 + 2]);
        }
        apply_cnot(sr, si, 1 << 3, 1 << 2);
        apply_cnot(sr, si, 1 << 2, 1 << 1);
        apply_cnot(sr, si, 1 << 1, 1 << 0);
        apply_cnot(sr, si, 1 << 0, 1 << 3);
        #pragma unroll
        for (int q = 0; q < NQ; ++q) {
            const int mask = 1 << (3 - q);
            apply_u3(sr, si, mask, w[q * 3 + 0], w[q * 3 + 1], w[q * 3 + 2]);
        }
        float z[NQ];
        #pragma unroll
        for (int q = 0; q < NQ; ++q) {
            const int mask = 1 << (3 - q);
            float acc = 0.f;
            #pragma unroll
            for (int i = 0; i < 16; ++i) {
                float pr = sr[i] * sr[i] + si[i] * si[i];
                acc += (i & mask) ? -pr : pr;
            }
            z[q] = acc;
        }
        float a = fcb[c];
        #pragma unroll
        for (int q = 0; q < NQ; ++q) a += z[q] * fcw[c * NQ + q];
        if (t == 0) s_att = 1.0f / (1.0f + expf(-a));
    }
    __syncthreads();
    const float att = s_att;

    // drain prefetched data
    __builtin_nontemporal_store(h0 * att, &op[t + 0 * BS]);
    __builtin_nontemporal_store(h1 * att, &op[t + 1 * BS]);
    __builtin_nontemporal_store(h2 * att, &op[t + 2 * BS]);
    __builtin_nontemporal_store(h3 * att, &op[t + 3 * BS]);
    __builtin_nontemporal_store(h4 * att, &op[t + 4 * BS]);
    __builtin_nontemporal_store(h5 * att, &op[t + 5 * BS]);
    __builtin_nontemporal_store(h6 * att, &op[t + 6 * BS]);
    __builtin_nontemporal_store(h7 * att, &op[t + 7 * BS]);

    // stream the remaining 56 iterations (L3-hot reads)
    #pragma unroll 4
    for (int i = PF; i < 64; ++i) {
        f32x4 v = xp[t + i * BS];
        __builtin_nontemporal_store(v * att, &op[t + i * BS]);
    }
}

extern "C" void kernel_launch(void* const* d_in, const int* in_sizes, int n_in,
                              void* d_out, int out_size, void* d_ws, size_t ws_size,
                              hipStream_t stream) {
    const float* x   = (const float*)d_in[0];
    const float* vw  = (const float*)d_in[1];
    const float* fcw = (const float*)d_in[2];
    const float* fcb = (const float*)d_in[3];
    float* out = (float*)d_out;

    float* part = (float*)d_ws;          // [3072], fully written each call

    mean_partial<<<NSEG, BS, 0, stream>>>(x, part);
    scale_vqc<<<NB, BS, 0, stream>>>(x, part, vw, fcw, fcb, out);
}

// Round 10
// 93.818 us; speedup vs baseline: 1.3364x; 1.0107x over previous
//
#include <hip/hip_runtime.h>
#include <math.h>

typedef float f32x4 __attribute__((ext_vector_type(4)));

#define NSEG 3072           // 4 segments per plane (both kernels)
#define SEG4 4096           // f32x4 per segment
#define BS 256
#define NCH 12
#define NQ 4
#define PLANE 65536         // floats per plane
#define PLANE4 16384        // f32x4 per plane
#define PF 8                // prefetched f32x4 per thread in kernel 2

// ---------------- VQC gate helpers (all indices compile-time) ----------------
__device__ __forceinline__ void apply_rz(float* sr, float* si, int mask, float theta) {
    float c, s;
    __sincosf(0.5f * theta, &s, &c);
    #pragma unroll
    for (int i = 0; i < 16; ++i) {
        float r = sr[i], im = si[i];
        if (i & mask) { sr[i] = r * c - im * s; si[i] = im * c + r * s; }
        else          { sr[i] = r * c + im * s; si[i] = im * c - r * s; }
    }
}

__device__ __forceinline__ void apply_ry(float* sr, float* si, int mask, float theta) {
    float c, s;
    __sincosf(0.5f * theta, &s, &c);
    #pragma unroll
    for (int i = 0; i < 16; ++i) {
        if (i & mask) continue;
        int jj = i | mask;
        float r0 = sr[i], i0 = si[i], r1 = sr[jj], i1 = si[jj];
        sr[i]  = c * r0 - s * r1;  si[i]  = c * i0 - s * i1;
        sr[jj] = s * r0 + c * r1;  si[jj] = s * i0 + c * i1;
    }
}

__device__ __forceinline__ void apply_cnot(float* sr, float* si, int mc, int mt) {
    #pragma unroll
    for (int i = 0; i < 16; ++i) {
        if ((i & mc) && !(i & mt)) {
            int jj = i | mt;
            float tr = sr[i], ti = si[i];
            sr[i] = sr[jj]; si[i] = si[jj];
            sr[jj] = tr;    si[jj] = ti;
        }
    }
}

__device__ __forceinline__ void apply_u3(float* sr, float* si, int mask,
                                         float theta, float phi, float lam) {
    float c = __cosf(0.5f * theta), s = __sinf(0.5f * theta);
    float cl, sl, cp, sp, cpl, spl;
    __sincosf(lam, &sl, &cl);
    __sincosf(phi, &sp, &cp);
    __sincosf(phi + lam, &spl, &cpl);
    float u01r = -cl * s, u01i = -sl * s;
    float u10r =  cp * s, u10i =  sp * s;
    float u11r =  cpl * c, u11i = spl * c;
    #pragma unroll
    for (int i = 0; i < 16; ++i) {
        if (i & mask) continue;
        int jj = i | mask;
        float r0 = sr[i], i0 = si[i], r1 = sr[jj], i1 = si[jj];
        sr[i]  = c * r0 + (u01r * r1 - u01i * i1);
        si[i]  = c * i0 + (u01r * i1 + u01i * r1);
        sr[jj] = (u10r * r0 - u10i * i0) + (u11r * r1 - u11i * i1);
        si[jj] = (u10r * i0 + u10i * r0) + (u11r * i1 + u11i * r1);
    }
}

// ---------------- Kernel 1: per-segment partial sums (temporal loads warm L3) ----
__global__ __launch_bounds__(256) void mean_partial(const float* __restrict__ x,
                                                    float* __restrict__ part) {
    const int seg = blockIdx.x;
    const f32x4* p = reinterpret_cast<const f32x4*>(x) + (size_t)seg * SEG4;
    const int t = threadIdx.x;
    float s0 = 0.f, s1 = 0.f, s2 = 0.f, s3 = 0.f;
    #pragma unroll
    for (int i = 0; i < 16; i += 4) {
        f32x4 a = p[t + (i + 0) * 256];
        f32x4 b = p[t + (i + 1) * 256];
        f32x4 c = p[t + (i + 2) * 256];
        f32x4 d = p[t + (i + 3) * 256];
        s0 += (a.x + a.y) + (a.z + a.w);
        s1 += (b.x + b.y) + (b.z + b.w);
        s2 += (c.x + c.y) + (c.z + c.w);
        s3 += (d.x + d.y) + (d.z + d.w);
    }
    float sum = (s0 + s1) + (s2 + s3);
    #pragma unroll
    for (int off = 32; off; off >>= 1) sum += __shfl_down(sum, off);
    __shared__ float wsum[4];
    if ((threadIdx.x & 63) == 0) wsum[threadIdx.x >> 6] = sum;
    __syncthreads();
    if (threadIdx.x == 0) part[seg] = (wsum[0] + wsum[1]) + (wsum[2] + wsum[3]);
}

// ---------------- Kernel 2: per-SEGMENT scale (3072 blocks, 12/CU) ----------------
__global__ __launch_bounds__(256) void scale_vqc(const float* __restrict__ x,
                                                 const float* __restrict__ part,
                                                 const float* __restrict__ w,
                                                 const float* __restrict__ fcw,
                                                 const float* __restrict__ fcb,
                                                 float* __restrict__ out) {
    const int seg = blockIdx.x;          // segment = plane*4 + quarter
    const int p = seg >> 2;              // plane = b*12 + c
    const int b = p / NCH, c = p - b * NCH;
    const int t = threadIdx.x;
    __shared__ float s_att;

    const f32x4* xp = reinterpret_cast<const f32x4*>(x) + (size_t)seg * SEG4;
    f32x4*       op = reinterpret_cast<f32x4*>(out)     + (size_t)seg * SEG4;

    // issue prefetch loads first — in flight during wave0's VQC
    f32x4 h0 = xp[t + 0 * BS], h1 = xp[t + 1 * BS];
    f32x4 h2 = xp[t + 2 * BS], h3 = xp[t + 3 * BS];
    f32x4 h4 = xp[t + 4 * BS], h5 = xp[t + 5 * BS];
    f32x4 h6 = xp[t + 6 * BS], h7 = xp[t + 7 * BS];

    if (t < 64) {   // wave 0 only: VQC (redundant across its 64 lanes)
        float m[NCH];
        #pragma unroll
        for (int cc = 0; cc < NCH; ++cc) {
            const float* q = &part[(size_t)(b * NCH + cc) * 4];
            m[cc] = ((q[0] + q[1]) + (q[2] + q[3])) * (1.0f / (float)PLANE);
        }
        float sr[16], si[16];
        #pragma unroll
        for (int i = 0; i < 16; ++i) { sr[i] = 0.25f; si[i] = 0.f; }
        #pragma unroll
        for (int q = 0; q < NQ; ++q) {
            const int mask = 1 << (3 - q);
            apply_rz(sr, si, mask, m[q * 3 + 0]);
            apply_ry(sr, si, mask, m[q * 3 + 1]);
            apply_rz(sr, si, mask, m[q * 3 + 2]);
        }
        apply_cnot(sr, si, 1 << 3, 1 << 2);
        apply_cnot(sr, si, 1 << 2, 1 << 1);
        apply_cnot(sr, si, 1 << 1, 1 << 0);
        apply_cnot(sr, si, 1 << 0, 1 << 3);
        #pragma unroll
        for (int q = 0; q < NQ; ++q) {
            const int mask = 1 << (3 - q);
            apply_u3(sr, si, mask, w[q * 3 + 0], w[q * 3 + 1], w[q * 3 + 2]);
        }
        float z[NQ];
        #pragma unroll
        for (int q = 0; q < NQ; ++q) {
            const int mask = 1 << (3 - q);
            float acc = 0.f;
            #pragma unroll
            for (int i = 0; i < 16; ++i) {
                float pr = sr[i] * sr[i] + si[i] * si[i];
                acc += (i & mask) ? -pr : pr;
            }
            z[q] = acc;
        }
        float a = fcb[c];
        #pragma unroll
        for (int q = 0; q < NQ; ++q) a += z[q] * fcw[c * NQ + q];
        if (t == 0) s_att = 1.0f / (1.0f + expf(-a));
    }
    __syncthreads();
    const float att = s_att;

    // drain prefetched data
    __builtin_nontemporal_store(h0 * att, &op[t + 0 * BS]);
    __builtin_nontemporal_store(h1 * att, &op[t + 1 * BS]);
    __builtin_nontemporal_store(h2 * att, &op[t + 2 * BS]);
    __builtin_nontemporal_store(h3 * att, &op[t + 3 * BS]);
    __builtin_nontemporal_store(h4 * att, &op[t + 4 * BS]);
    __builtin_nontemporal_store(h5 * att, &op[t + 5 * BS]);
    __builtin_nontemporal_store(h6 * att, &op[t + 6 * BS]);
    __builtin_nontemporal_store(h7 * att, &op[t + 7 * BS]);

    // stream the remaining 8 iterations (L3-hot reads)
    #pragma unroll
    for (int i = PF; i < 16; ++i) {
        f32x4 v = xp[t + i * BS];
        __builtin_nontemporal_store(v * att, &op[t + i * BS]);
    }
}

extern "C" void kernel_launch(void* const* d_in, const int* in_sizes, int n_in,
                              void* d_out, int out_size, void* d_ws, size_t ws_size,
                              hipStream_t stream) {
    const float* x   = (const float*)d_in[0];
    const float* vw  = (const float*)d_in[1];
    const float* fcw = (const float*)d_in[2];
    const float* fcb = (const float*)d_in[3];
    float* out = (float*)d_out;

    float* part = (float*)d_ws;          // [3072], fully written each call

    mean_partial<<<NSEG, BS, 0, stream>>>(x, part);
    scale_vqc<<<NSEG, BS, 0, stream>>>(x, part, vw, fcw, fcb, out);
}